// Round 3
// baseline (2641.900 us; speedup 1.0000x reference)
//
#include <hip/hip_runtime.h>
#include <hip/hip_bf16.h>
#include <math.h>

#define B_SZ 4096
#define L_SZ 512
#define A_SZ 64
#define HD_SZ 1024
#define H_SZ 32

typedef __attribute__((ext_vector_type(8))) short bf16x8;
typedef __attribute__((ext_vector_type(4))) short s16x4;
typedef __attribute__((ext_vector_type(4))) float f32x4;

#define GLDS16(gsrc, ldst) __builtin_amdgcn_global_load_lds(              \
    (const __attribute__((address_space(1))) void*)(gsrc),                \
    (__attribute__((address_space(3))) void*)(ldst), 16, 0, 0)

template <int N> __device__ __forceinline__ void vmwait() {
  asm volatile("s_waitcnt vmcnt(%0)" :: "n"(N) : "memory");
}

__device__ __forceinline__ float gelu_exact(float x) {
  return 0.5f * x * (1.0f + erff(x * 0.70710678118654752f));
}

// ---------------------------------------------------------------------------
// 3-stage counted-vmcnt pipelined GEMM: C[M,N] = A[M,K](bf16) x Wt[N,K](bf16)
// BK=32, 4 waves (2x2), wave-tile (BM/2)x(BN/2), b128 fragment reads with
// contiguous-8 k-chunks (sigma-consistent for A and B), XOR-swizzled LDS.
// MODE 0: outf = acc + bias[n]                                  (f32)
// MODE 1: dz = acc+bias; zn = z_cur + gs*dz; write z_cur, znb, traj slice
// MODE 3: g = gelu(acc+bias); atomicAdd(sig_acc[row*H+t], g*uW2[n]) (fused)
// ---------------------------------------------------------------------------
template <int BM, int BN, int MODE>
__global__ __launch_bounds__(256, 2) void gemm_kernel(
    const __hip_bfloat16* __restrict__ A0, int a0s,
    const __hip_bfloat16* __restrict__ A1, int a1s, int ksplit,
    const __hip_bfloat16* __restrict__ Bt,
    const float* __restrict__ bias,
    int N, int K,
    float* __restrict__ outf,
    float* __restrict__ z_cur,
    __hip_bfloat16* __restrict__ znb,
    float* __restrict__ traj,
    const float* __restrict__ gate,
    int t,
    const float* __restrict__ uW2,
    float* __restrict__ sig_acc) {
  constexpr int BK = 32;
  constexpr int FM = BM / 32, FN = BN / 32;
  constexpr int ABYTES = BM * 64;        // BK*2 bytes per row
  constexpr int BUFB = (BM + BN) * 64;   // bytes per pipeline buffer
  constexpr int LOADS = (BM + BN) / 64;  // GLDS16 per thread per k-tile
  __shared__ __align__(16) char lds[3 * BUFB];

  const int tid = threadIdx.x;
  const int m0 = blockIdx.x * BM, n0 = blockIdx.y * BN;
  const int wave = tid >> 6, lane = tid & 63;
  const int l15 = lane & 15, lg = lane >> 4;
  const int wm = wave >> 1, wn = wave & 1;
  const int NK = K / BK;

  f32x4 acc[FM][FN];
#pragma unroll
  for (int mi = 0; mi < FM; ++mi)
#pragma unroll
    for (int ni = 0; ni < FN; ++ni) acc[mi][ni] = (f32x4){0.f, 0.f, 0.f, 0.f};

  auto stage = [&](int buf, int kt) {
    char* dst = lds + buf * BUFB;
    const int k0 = kt * BK;
    const __hip_bfloat16* Aptr;
    int As, kloc;
    if (k0 < ksplit) { Aptr = A0; As = a0s; kloc = k0; }
    else             { Aptr = A1; As = a1s; kloc = k0 - ksplit; }
#pragma unroll
    for (int i = 0; i < BM / 64; ++i) {
      int off = tid * 16 + i * 4096;
      int r = off >> 6;
      int csw = (off & 63) ^ ((r & 3) << 4);
      GLDS16(Aptr + (size_t)(m0 + r) * As + kloc + (csw >> 1), dst + off);
    }
#pragma unroll
    for (int i = 0; i < BN / 64; ++i) {
      int off = tid * 16 + i * 4096;
      int r = off >> 6;
      int csw = (off & 63) ^ ((r & 3) << 4);
      GLDS16(Bt + (size_t)(n0 + r) * K + k0 + (csw >> 1), dst + ABYTES + off);
    }
  };

  // per-lane LDS fragment base offsets (row&3 == l15&3, mi steps = +1024B)
  const int xr = (l15 & 3) << 4;
  const int abase = (wm * (FM * 16) + l15) * 64 + ((lg * 16) ^ xr);
  const int bbase = ABYTES + (wn * (FN * 16) + l15) * 64 + ((lg * 16) ^ xr);

  // prologue: 2 tiles in flight
  stage(0, 0);
  stage(1, 1);

  int buf = 0;
  for (int kt = 0; kt < NK; ++kt) {
    if (kt + 2 < NK) {
      int b2 = buf + 2; if (b2 >= 3) b2 -= 3;
      stage(b2, kt + 2);
    }
    if (kt + 2 < NK)      vmwait<2 * LOADS>();
    else if (kt + 1 < NK) vmwait<LOADS>();
    else                  vmwait<0>();
    __builtin_amdgcn_s_barrier();
    asm volatile("" ::: "memory");

    const char* lb = lds + buf * BUFB;
    bf16x8 a_[FM], b_[FN];
#pragma unroll
    for (int mi = 0; mi < FM; ++mi)
      a_[mi] = *(const bf16x8*)(lb + abase + mi * 1024);
#pragma unroll
    for (int ni = 0; ni < FN; ++ni)
      b_[ni] = *(const bf16x8*)(lb + bbase + ni * 1024);
#pragma unroll
    for (int mi = 0; mi < FM; ++mi)
#pragma unroll
      for (int ni = 0; ni < FN; ++ni)
        acc[mi][ni] = __builtin_amdgcn_mfma_f32_16x16x32_bf16(
            a_[mi], b_[ni], acc[mi][ni], 0, 0, 0);

    asm volatile("" ::: "memory");
    __builtin_amdgcn_s_barrier();
    buf = (buf + 1 == 3) ? 0 : buf + 1;
  }

  // ---- epilogue -----------------------------------------------------------
  if constexpr (MODE == 3) {
#pragma unroll
    for (int mi = 0; mi < FM; ++mi) {
      float p[4] = {0.f, 0.f, 0.f, 0.f};
#pragma unroll
      for (int ni = 0; ni < FN; ++ni) {
        int gcol = n0 + wn * (FN * 16) + ni * 16 + l15;
        float bv = bias[gcol];
        float w2 = uW2[gcol];
#pragma unroll
        for (int r = 0; r < 4; ++r)
          p[r] += gelu_exact(acc[mi][ni][r] + bv) * w2;
      }
#pragma unroll
      for (int o = 1; o < 16; o <<= 1) {
#pragma unroll
        for (int r = 0; r < 4; ++r) p[r] += __shfl_xor(p[r], o);
      }
      if (l15 == 0) {
        int rowb = m0 + wm * (FM * 16) + mi * 16 + lg * 4;
#pragma unroll
        for (int r = 0; r < 4; ++r)
          atomicAdd(&sig_acc[(size_t)(rowb + r) * H_SZ + t], p[r]);
      }
    }
  } else {
    float gs = 0.f;
    if constexpr (MODE == 1) gs = 1.f / (1.f + expf(-gate[0]));
#pragma unroll
    for (int mi = 0; mi < FM; ++mi) {
#pragma unroll
      for (int ni = 0; ni < FN; ++ni) {
        int gcol = n0 + wn * (FN * 16) + ni * 16 + l15;
        float bv = bias[gcol];
#pragma unroll
        for (int r = 0; r < 4; ++r) {
          int grow = m0 + wm * (FM * 16) + mi * 16 + lg * 4 + r;
          float v = acc[mi][ni][r] + bv;
          if constexpr (MODE == 0) {
            outf[(size_t)grow * N + gcol] = v;
          } else {
            size_t zi = (size_t)grow * L_SZ + gcol;
            float zn = z_cur[zi] + gs * v;
            z_cur[zi] = zn;
            znb[zi] = __float2bfloat16(zn);
            traj[(size_t)grow * (H_SZ * L_SZ) + (size_t)t * L_SZ + gcol] = zn;
          }
        }
      }
    }
  }
}

// ---------------------------------------------------------------------------
// Row LayerNorm (N=1024) + GELU, fp32 in -> bf16 out. One block per row.
// ---------------------------------------------------------------------------
__global__ __launch_bounds__(256) void ln_gelu_kernel(
    const float* __restrict__ x, const float* __restrict__ gam,
    const float* __restrict__ bet, __hip_bfloat16* __restrict__ out) {
  constexpr int N = HD_SZ;
  const int row = blockIdx.x;
  const int tid = threadIdx.x, lane = tid & 63, wave = tid >> 6;
  const float* xr = x + (size_t)row * N;
  f32x4 v = *(const f32x4*)(xr + tid * 4);
  float s = v[0] + v[1] + v[2] + v[3];
  float s2 = v[0] * v[0] + v[1] * v[1] + v[2] * v[2] + v[3] * v[3];
#pragma unroll
  for (int o = 32; o; o >>= 1) {
    s += __shfl_xor(s, o);
    s2 += __shfl_xor(s2, o);
  }
  __shared__ float as_[4], as2_[4];
  if (lane == 0) { as_[wave] = s; as2_[wave] = s2; }
  __syncthreads();
  s = as_[0] + as_[1] + as_[2] + as_[3];
  s2 = as2_[0] + as2_[1] + as2_[2] + as2_[3];
  float mean = s * (1.f / N);
  float var = s2 * (1.f / N) - mean * mean;
  float rstd = rsqrtf(var + 1e-5f);
  f32x4 g = *(const f32x4*)(gam + tid * 4);
  f32x4 b = *(const f32x4*)(bet + tid * 4);
  union { __hip_bfloat16 h[4]; s16x4 sv; } o;
#pragma unroll
  for (int j = 0; j < 4; ++j) {
    float y = (v[j] - mean) * rstd * g[j] + b[j];
    o.h[j] = __float2bfloat16(gelu_exact(y));
  }
  *(s16x4*)(out + (size_t)row * N + tid * 4) = o.sv;
}

// ---------------------------------------------------------------------------
// prep / misc kernels
// ---------------------------------------------------------------------------
__global__ void transpose_cvt(const float* __restrict__ in,
                              __hip_bfloat16* __restrict__ out, int K, int N) {
  __shared__ float tile[32][33];
  const int n0 = blockIdx.x * 32, k0 = blockIdx.y * 32;
  const int tx = threadIdx.x, ty = threadIdx.y;  // (32, 8)
#pragma unroll
  for (int i = 0; i < 32; i += 8)
    tile[ty + i][tx] = in[(size_t)(k0 + ty + i) * N + (n0 + tx)];
  __syncthreads();
#pragma unroll
  for (int i = 0; i < 32; i += 8)
    out[(size_t)(n0 + ty + i) * K + (k0 + tx)] = __float2bfloat16(tile[tx][ty + i]);
}

__global__ void cvt_bf16_kernel(const float* __restrict__ in,
                                __hip_bfloat16* __restrict__ out, int n4) {
  int i = blockIdx.x * 256 + threadIdx.x;
  if (i >= n4) return;
  f32x4 v = ((const f32x4*)in)[i];
  union { __hip_bfloat16 h[4]; s16x4 sv; } o;
#pragma unroll
  for (int j = 0; j < 4; ++j) o.h[j] = __float2bfloat16(v[j]);
  ((s16x4*)out)[i] = o.sv;
}

__global__ void init_z_kernel(const float* __restrict__ z0,
                              float* __restrict__ z_cur,
                              __hip_bfloat16* __restrict__ znb, int n4) {
  int i = blockIdx.x * 256 + threadIdx.x;
  if (i >= n4) return;
  f32x4 v = ((const f32x4*)z0)[i];
  ((f32x4*)z_cur)[i] = v;
  union { __hip_bfloat16 h[4]; s16x4 sv; } o;
#pragma unroll
  for (int j = 0; j < 4; ++j) o.h[j] = __float2bfloat16(v[j]);
  ((s16x4*)znb)[i] = o.sv;
}

__global__ void zero_kernel(float* __restrict__ p, int n) {
  int i = blockIdx.x * 256 + threadIdx.x;
  if (i < n) p[i] = 0.f;
}

__global__ void softplus_kernel(const float* __restrict__ acc,
                                const float* __restrict__ ub2,
                                float* __restrict__ out, int n) {
  int i = blockIdx.x * 256 + threadIdx.x;
  if (i >= n) return;
  float v = acc[i] + ub2[0];
  out[i] = v > 20.f ? v : log1pf(expf(v));
}

// ---------------------------------------------------------------------------
extern "C" void kernel_launch(void* const* d_in, const int* in_sizes, int n_in,
                              void* d_out, int out_size, void* d_ws,
                              size_t ws_size, hipStream_t stream) {
  const float* z0      = (const float*)d_in[0];
  const float* actions = (const float*)d_in[1];
  const float* W1  = (const float*)d_in[2];
  const float* b1  = (const float*)d_in[3];
  const float* g1  = (const float*)d_in[4];
  const float* be1 = (const float*)d_in[5];
  const float* W2  = (const float*)d_in[6];
  const float* b2  = (const float*)d_in[7];
  const float* g2  = (const float*)d_in[8];
  const float* be2 = (const float*)d_in[9];
  const float* W3  = (const float*)d_in[10];
  const float* b3  = (const float*)d_in[11];
  const float* uW1 = (const float*)d_in[12];
  const float* ub1 = (const float*)d_in[13];
  const float* uW2 = (const float*)d_in[14];
  const float* ub2 = (const float*)d_in[15];
  const float* gate = (const float*)d_in[16];

  char* w = (char*)d_ws;
  __hip_bfloat16* W1t = (__hip_bfloat16*)w;  w += (size_t)(L_SZ + A_SZ) * HD_SZ * 2;
  __hip_bfloat16* W2t = (__hip_bfloat16*)w;  w += (size_t)HD_SZ * HD_SZ * 2;
  __hip_bfloat16* W3t = (__hip_bfloat16*)w;  w += (size_t)HD_SZ * L_SZ * 2;
  __hip_bfloat16* uW1t = (__hip_bfloat16*)w; w += (size_t)L_SZ * (HD_SZ / 2) * 2;
  __hip_bfloat16* actb = (__hip_bfloat16*)w; w += (size_t)B_SZ * H_SZ * A_SZ * 2;
  float* z_cur = (float*)w;                  w += (size_t)B_SZ * L_SZ * 4;
  __hip_bfloat16* znb = (__hip_bfloat16*)w;  w += (size_t)B_SZ * L_SZ * 2;
  float* tws = (float*)w;                    w += (size_t)B_SZ * HD_SZ * 4;
  __hip_bfloat16* hb = (__hip_bfloat16*)w;   w += (size_t)B_SZ * HD_SZ * 2;
  float* sig_acc = (float*)w;                w += (size_t)B_SZ * H_SZ * 4;

  float* trajOut = (float*)d_out;
  float* sigsOut = (float*)d_out + (size_t)B_SZ * H_SZ * L_SZ;

  dim3 tb(32, 8);
  transpose_cvt<<<dim3(HD_SZ / 32, (L_SZ + A_SZ) / 32), tb, 0, stream>>>(W1, W1t, L_SZ + A_SZ, HD_SZ);
  transpose_cvt<<<dim3(HD_SZ / 32, HD_SZ / 32), tb, 0, stream>>>(W2, W2t, HD_SZ, HD_SZ);
  transpose_cvt<<<dim3(L_SZ / 32, HD_SZ / 32), tb, 0, stream>>>(W3, W3t, HD_SZ, L_SZ);
  transpose_cvt<<<dim3((HD_SZ / 2) / 32, L_SZ / 32), tb, 0, stream>>>(uW1, uW1t, L_SZ, HD_SZ / 2);

  cvt_bf16_kernel<<<(B_SZ * H_SZ * A_SZ / 4 + 255) / 256, 256, 0, stream>>>(
      actions, actb, B_SZ * H_SZ * A_SZ / 4);
  init_z_kernel<<<(B_SZ * L_SZ / 4 + 255) / 256, 256, 0, stream>>>(
      z0, z_cur, znb, B_SZ * L_SZ / 4);
  zero_kernel<<<(B_SZ * H_SZ + 255) / 256, 256, 0, stream>>>(sig_acc, B_SZ * H_SZ);

  const int KSPLIT_NONE = 1 << 30;
  for (int t = 0; t < H_SZ; ++t) {
    // GEMM1: za @ W1 + b1 -> tws   (A = [znb | actions[:,t,:]], ksplit=512)
    gemm_kernel<128, 128, 0><<<dim3(B_SZ / 128, HD_SZ / 128), 256, 0, stream>>>(
        znb, L_SZ, actb + (size_t)t * A_SZ, H_SZ * A_SZ, L_SZ, W1t, b1,
        HD_SZ, L_SZ + A_SZ, tws, nullptr, nullptr, nullptr, nullptr, 0,
        nullptr, nullptr);
    ln_gelu_kernel<<<B_SZ, 256, 0, stream>>>(tws, g1, be1, hb);
    // GEMM2: h1 @ W2 + b2 -> tws
    gemm_kernel<128, 128, 0><<<dim3(B_SZ / 128, HD_SZ / 128), 256, 0, stream>>>(
        hb, HD_SZ, nullptr, 0, KSPLIT_NONE, W2t, b2,
        HD_SZ, HD_SZ, tws, nullptr, nullptr, nullptr, nullptr, 0,
        nullptr, nullptr);
    ln_gelu_kernel<<<B_SZ, 256, 0, stream>>>(tws, g2, be2, hb);
    // GEMM3: h2 @ W3 + b3 -> z update + traj write + znb
    gemm_kernel<64, 128, 1><<<dim3(B_SZ / 64, L_SZ / 128), 256, 0, stream>>>(
        hb, HD_SZ, nullptr, 0, KSPLIT_NONE, W3t, b3,
        L_SZ, HD_SZ, nullptr, z_cur, znb, trajOut, gate, t,
        nullptr, nullptr);
    // GEMM4: z_next @ uW1 + ub1 -> gelu -> dot(uW2) partials -> sig_acc
    gemm_kernel<64, 128, 3><<<dim3(B_SZ / 64, (HD_SZ / 2) / 128), 256, 0, stream>>>(
        znb, L_SZ, nullptr, 0, KSPLIT_NONE, uW1t, ub1,
        HD_SZ / 2, L_SZ, nullptr, nullptr, nullptr, nullptr, nullptr, t,
        uW2, sig_acc);
  }
  softplus_kernel<<<(B_SZ * H_SZ + 255) / 256, 256, 0, stream>>>(
      sig_acc, ub2, sigsOut, B_SZ * H_SZ);
}

// Round 4
// 2384.498 us; speedup vs baseline: 1.1079x; 1.1079x over previous
//
#include <hip/hip_runtime.h>
#include <hip/hip_bf16.h>
#include <math.h>

#define B_SZ 4096
#define L_SZ 512
#define A_SZ 64
#define HD_SZ 1024
#define H_SZ 32

typedef __attribute__((ext_vector_type(8))) short bf16x8;
typedef __attribute__((ext_vector_type(4))) short s16x4;
typedef __attribute__((ext_vector_type(4))) float f32x4;

#define GLDS16(gsrc, ldst) __builtin_amdgcn_global_load_lds(              \
    (const __attribute__((address_space(1))) void*)(gsrc),                \
    (__attribute__((address_space(3))) void*)(ldst), 16, 0, 0)

__device__ __forceinline__ float gelu_exact(float x) {
  return 0.5f * x * (1.0f + erff(x * 0.70710678118654752f));
}

// ---------------------------------------------------------------------------
// 2-buffer BK=64 GEMM: C[M,N] = A[M,K](bf16) x Wt[N,K](bf16)
// 4 waves (2 wm x 2 wn), wave-tile 32x64, 16x16x32 MFMA, b128 frag reads,
// XOR-swizzled LDS (byte col ^ ((row&7)<<4)), 64x128 block tile.
// MODE 0: outf = acc + bias[n]                                  (f32)
// MODE 4: n0<512:  dz path: zn = z_cur + gs*(acc+bias); write z_cur, znb, traj
//         n0>=512: du path: zu += gs*(acc+bias); g=gelu(zu+ub1); atomic sig
// ---------------------------------------------------------------------------
template <int BM, int BN, int MODE>
__global__ __launch_bounds__(256, 2) void gemm_kernel(
    const __hip_bfloat16* __restrict__ A0, int a0s,
    const __hip_bfloat16* __restrict__ A1, int a1s, int ksplit,
    const __hip_bfloat16* __restrict__ Bt,
    const float* __restrict__ bias,
    int N, int K,
    float* __restrict__ outf,
    float* __restrict__ z_cur,
    __hip_bfloat16* __restrict__ znb,
    float* __restrict__ traj,
    const float* __restrict__ gate,
    int t,
    float* __restrict__ zu,
    const float* __restrict__ ub1v,
    const float* __restrict__ uW2,
    float* __restrict__ sig_acc) {
  constexpr int BK = 64;
  constexpr int ROWB = BK * 2;            // 128 bytes per row
  constexpr int FM = BM / 32, FN = BN / 32;
  constexpr int ABYTES = BM * ROWB;
  constexpr int BUFB = (BM + BN) * ROWB;  // bytes per buffer
  __shared__ __align__(16) char lds[2 * BUFB];

  const int tid = threadIdx.x;
  const int m0 = blockIdx.x * BM, n0 = blockIdx.y * BN;
  const int wave = tid >> 6, lane = tid & 63;
  const int l15 = lane & 15, lg = lane >> 4;
  const int wm = wave >> 1, wn = wave & 1;
  const int NK = K / BK;

  f32x4 acc[FM][FN];
#pragma unroll
  for (int mi = 0; mi < FM; ++mi)
#pragma unroll
    for (int ni = 0; ni < FN; ++ni) acc[mi][ni] = (f32x4){0.f, 0.f, 0.f, 0.f};

  auto stage = [&](int buf, int kt) {
    char* dst = lds + buf * BUFB;
    const int k0 = kt * BK;
    const __hip_bfloat16* Aptr;
    int As, kloc;
    if (k0 < ksplit) { Aptr = A0; As = a0s; kloc = k0; }
    else             { Aptr = A1; As = a1s; kloc = k0 - ksplit; }
#pragma unroll
    for (int i = 0; i < BM / 32; ++i) {
      int off = tid * 16 + i * 4096;
      int r = off >> 7;
      int csw = (off & 127) ^ ((r & 7) << 4);
      GLDS16(Aptr + (size_t)(m0 + r) * As + kloc + (csw >> 1), dst + off);
    }
#pragma unroll
    for (int i = 0; i < BN / 32; ++i) {
      int off = tid * 16 + i * 4096;
      int r = off >> 7;
      int csw = (off & 127) ^ ((r & 7) << 4);
      GLDS16(Bt + (size_t)(n0 + r) * K + k0 + (csw >> 1), dst + ABYTES + off);
    }
  };

  // per-lane fragment byte offsets (row&7 == l15&7 for all frags)
  const int xrow = (l15 & 7) << 4;
  const int offs0 = (lg * 16) ^ xrow;      // k-substep 0
  const int aoff = (wm * (FM * 16) + l15) * ROWB;
  const int boff = ABYTES + (wn * (FN * 16) + l15) * ROWB;

  stage(0, 0);
  asm volatile("s_waitcnt vmcnt(0)" ::: "memory");
  __syncthreads();

  int buf = 0;
  for (int kt = 0; kt < NK; ++kt) {
    if (kt + 1 < NK) stage(buf ^ 1, kt + 1);

    const char* lb = lds + buf * BUFB;
    bf16x8 a_[FM][2], b_[FN][2];
#pragma unroll
    for (int mi = 0; mi < FM; ++mi) {
      a_[mi][0] = *(const bf16x8*)(lb + aoff + mi * (16 * ROWB) + offs0);
      a_[mi][1] = *(const bf16x8*)(lb + aoff + mi * (16 * ROWB) + (offs0 ^ 64));
    }
#pragma unroll
    for (int ni = 0; ni < FN; ++ni) {
      b_[ni][0] = *(const bf16x8*)(lb + boff + ni * (16 * ROWB) + offs0);
      b_[ni][1] = *(const bf16x8*)(lb + boff + ni * (16 * ROWB) + (offs0 ^ 64));
    }
#pragma unroll
    for (int s = 0; s < 2; ++s)
#pragma unroll
      for (int mi = 0; mi < FM; ++mi)
#pragma unroll
        for (int ni = 0; ni < FN; ++ni)
          acc[mi][ni] = __builtin_amdgcn_mfma_f32_16x16x32_bf16(
              a_[mi][s], b_[ni][s], acc[mi][ni], 0, 0, 0);

    asm volatile("s_waitcnt vmcnt(0)" ::: "memory");
    __syncthreads();
    buf ^= 1;
  }

  // ---- epilogue -----------------------------------------------------------
  if constexpr (MODE == 0) {
#pragma unroll
    for (int mi = 0; mi < FM; ++mi) {
#pragma unroll
      for (int ni = 0; ni < FN; ++ni) {
        int gcol = n0 + wn * (FN * 16) + ni * 16 + l15;
        float bv = bias[gcol];
#pragma unroll
        for (int r = 0; r < 4; ++r) {
          int grow = m0 + wm * (FM * 16) + mi * 16 + lg * 4 + r;
          outf[(size_t)grow * N + gcol] = acc[mi][ni][r] + bv;
        }
      }
    }
  } else {
    const float gs = 1.f / (1.f + expf(-gate[0]));
    if (n0 < L_SZ) {
      // dz path: z update + traj + znb
#pragma unroll
      for (int mi = 0; mi < FM; ++mi) {
#pragma unroll
        for (int ni = 0; ni < FN; ++ni) {
          int gcol = n0 + wn * (FN * 16) + ni * 16 + l15;
          float bv = bias[gcol];
#pragma unroll
          for (int r = 0; r < 4; ++r) {
            int grow = m0 + wm * (FM * 16) + mi * 16 + lg * 4 + r;
            size_t zi = (size_t)grow * L_SZ + gcol;
            float zn = z_cur[zi] + gs * (acc[mi][ni][r] + bv);
            z_cur[zi] = zn;
            znb[zi] = __float2bfloat16(zn);
            traj[(size_t)grow * (H_SZ * L_SZ) + (size_t)t * L_SZ + gcol] = zn;
          }
        }
      }
    } else {
      // du path: zu update + gelu + uW2 dot -> sig_acc
#pragma unroll
      for (int mi = 0; mi < FM; ++mi) {
        float p[4] = {0.f, 0.f, 0.f, 0.f};
#pragma unroll
        for (int ni = 0; ni < FN; ++ni) {
          int gcol = n0 + wn * (FN * 16) + ni * 16 + l15;
          int j = gcol - L_SZ;
          float bv = bias[gcol];
          float ub = ub1v[j];
          float w2 = uW2[j];
#pragma unroll
          for (int r = 0; r < 4; ++r) {
            int grow = m0 + wm * (FM * 16) + mi * 16 + lg * 4 + r;
            size_t ui = (size_t)grow * L_SZ + j;
            float zun = zu[ui] + gs * (acc[mi][ni][r] + bv);
            zu[ui] = zun;
            p[r] += gelu_exact(zun + ub) * w2;
          }
        }
#pragma unroll
        for (int o = 1; o < 16; o <<= 1) {
#pragma unroll
          for (int r = 0; r < 4; ++r) p[r] += __shfl_xor(p[r], o);
        }
        if (l15 == 0) {
          int rowb = m0 + wm * (FM * 16) + mi * 16 + lg * 4;
#pragma unroll
          for (int r = 0; r < 4; ++r)
            atomicAdd(&sig_acc[(size_t)(rowb + r) * H_SZ + t], p[r]);
        }
      }
    }
  }
}

// ---------------------------------------------------------------------------
// Row LayerNorm (N=1024) + GELU, fp32 in -> bf16 out. One block per row.
// ---------------------------------------------------------------------------
__global__ __launch_bounds__(256) void ln_gelu_kernel(
    const float* __restrict__ x, const float* __restrict__ gam,
    const float* __restrict__ bet, __hip_bfloat16* __restrict__ out) {
  constexpr int N = HD_SZ;
  const int row = blockIdx.x;
  const int tid = threadIdx.x, lane = tid & 63, wave = tid >> 6;
  const float* xr = x + (size_t)row * N;
  f32x4 v = *(const f32x4*)(xr + tid * 4);
  float s = v[0] + v[1] + v[2] + v[3];
  float s2 = v[0] * v[0] + v[1] * v[1] + v[2] * v[2] + v[3] * v[3];
#pragma unroll
  for (int o = 32; o; o >>= 1) {
    s += __shfl_xor(s, o);
    s2 += __shfl_xor(s2, o);
  }
  __shared__ float as_[4], as2_[4];
  if (lane == 0) { as_[wave] = s; as2_[wave] = s2; }
  __syncthreads();
  s = as_[0] + as_[1] + as_[2] + as_[3];
  s2 = as2_[0] + as2_[1] + as2_[2] + as2_[3];
  float mean = s * (1.f / N);
  float var = s2 * (1.f / N) - mean * mean;
  float rstd = rsqrtf(var + 1e-5f);
  f32x4 g = *(const f32x4*)(gam + tid * 4);
  f32x4 b = *(const f32x4*)(bet + tid * 4);
  union { __hip_bfloat16 h[4]; s16x4 sv; } o;
#pragma unroll
  for (int j = 0; j < 4; ++j) {
    float y = (v[j] - mean) * rstd * g[j] + b[j];
    o.h[j] = __float2bfloat16(gelu_exact(y));
  }
  *(s16x4*)(out + (size_t)row * N + tid * 4) = o.sv;
}

// ---------------------------------------------------------------------------
// prep / misc kernels
// ---------------------------------------------------------------------------
__global__ void transpose_cvt(const float* __restrict__ in,
                              __hip_bfloat16* __restrict__ out, int K, int N) {
  __shared__ float tile[32][33];
  const int n0 = blockIdx.x * 32, k0 = blockIdx.y * 32;
  const int tx = threadIdx.x, ty = threadIdx.y;  // (32, 8)
#pragma unroll
  for (int i = 0; i < 32; i += 8)
    tile[ty + i][tx] = in[(size_t)(k0 + ty + i) * N + (n0 + tx)];
  __syncthreads();
#pragma unroll
  for (int i = 0; i < 32; i += 8)
    out[(size_t)(n0 + ty + i) * K + (k0 + tx)] = __float2bfloat16(tile[tx][ty + i]);
}

// W34t[j][k] = sum_i W3[k][i]*uW1[i][j]  -> bf16 into W3c rows [512, 1024)
__global__ __launch_bounds__(256) void w34_kernel(
    const float* __restrict__ W3, const float* __restrict__ uW1,
    __hip_bfloat16* __restrict__ W3c) {
  __shared__ float tA[16][17];  // [k-local][i-local]
  __shared__ float tB[16][17];  // [i-local][j-local]
  const int k0 = blockIdx.x * 16, j0 = blockIdx.y * 16;
  const int tx = threadIdx.x & 15, ty = threadIdx.x >> 4;
  float acc = 0.f;
  for (int i0 = 0; i0 < L_SZ; i0 += 16) {
    tA[ty][tx] = W3[(size_t)(k0 + ty) * L_SZ + i0 + tx];
    tB[ty][tx] = uW1[(size_t)(i0 + ty) * (HD_SZ / 2) + j0 + tx];
    __syncthreads();
#pragma unroll
    for (int i = 0; i < 16; ++i) acc += tA[ty][i] * tB[i][tx];
    __syncthreads();
  }
  W3c[(size_t)(L_SZ + j0 + tx) * HD_SZ + k0 + ty] = __float2bfloat16(acc);
}

// bias3c[0:512) = b3 ; bias3c[512+j] = sum_i b3[i]*uW1[i][j]
__global__ void bias3_kernel(const float* __restrict__ b3,
                             const float* __restrict__ uW1,
                             float* __restrict__ bias3c) {
  int j = blockIdx.x * 256 + threadIdx.x;
  if (j >= L_SZ) return;
  bias3c[j] = b3[j];
  float s = 0.f;
  for (int i = 0; i < L_SZ; ++i) s += b3[i] * uW1[(size_t)i * (HD_SZ / 2) + j];
  bias3c[L_SZ + j] = s;
}

__global__ void cvt_bf16_kernel(const float* __restrict__ in,
                                __hip_bfloat16* __restrict__ out, int n4) {
  int i = blockIdx.x * 256 + threadIdx.x;
  if (i >= n4) return;
  f32x4 v = ((const f32x4*)in)[i];
  union { __hip_bfloat16 h[4]; s16x4 sv; } o;
#pragma unroll
  for (int j = 0; j < 4; ++j) o.h[j] = __float2bfloat16(v[j]);
  ((s16x4*)out)[i] = o.sv;
}

__global__ void init_z_kernel(const float* __restrict__ z0,
                              float* __restrict__ z_cur,
                              __hip_bfloat16* __restrict__ znb, int n4) {
  int i = blockIdx.x * 256 + threadIdx.x;
  if (i >= n4) return;
  f32x4 v = ((const f32x4*)z0)[i];
  ((f32x4*)z_cur)[i] = v;
  union { __hip_bfloat16 h[4]; s16x4 sv; } o;
#pragma unroll
  for (int j = 0; j < 4; ++j) o.h[j] = __float2bfloat16(v[j]);
  ((s16x4*)znb)[i] = o.sv;
}

__global__ void zero_kernel(float* __restrict__ p, int n) {
  int i = blockIdx.x * 256 + threadIdx.x;
  if (i < n) p[i] = 0.f;
}

__global__ void softplus_kernel(const float* __restrict__ acc,
                                const float* __restrict__ ub2,
                                float* __restrict__ out, int n) {
  int i = blockIdx.x * 256 + threadIdx.x;
  if (i >= n) return;
  float v = acc[i] + ub2[0];
  out[i] = v > 20.f ? v : log1pf(expf(v));
}

// ---------------------------------------------------------------------------
extern "C" void kernel_launch(void* const* d_in, const int* in_sizes, int n_in,
                              void* d_out, int out_size, void* d_ws,
                              size_t ws_size, hipStream_t stream) {
  const float* z0      = (const float*)d_in[0];
  const float* actions = (const float*)d_in[1];
  const float* W1  = (const float*)d_in[2];
  const float* b1  = (const float*)d_in[3];
  const float* g1  = (const float*)d_in[4];
  const float* be1 = (const float*)d_in[5];
  const float* W2  = (const float*)d_in[6];
  const float* b2  = (const float*)d_in[7];
  const float* g2  = (const float*)d_in[8];
  const float* be2 = (const float*)d_in[9];
  const float* W3  = (const float*)d_in[10];
  const float* b3  = (const float*)d_in[11];
  const float* uW1 = (const float*)d_in[12];
  const float* ub1 = (const float*)d_in[13];
  const float* uW2 = (const float*)d_in[14];
  const float* ub2 = (const float*)d_in[15];
  const float* gate = (const float*)d_in[16];

  char* w = (char*)d_ws;
  __hip_bfloat16* W1t = (__hip_bfloat16*)w;  w += (size_t)(L_SZ + A_SZ) * HD_SZ * 2;
  __hip_bfloat16* W2t = (__hip_bfloat16*)w;  w += (size_t)HD_SZ * HD_SZ * 2;
  __hip_bfloat16* W3c = (__hip_bfloat16*)w;  w += (size_t)HD_SZ * HD_SZ * 2;  // [W3t | W34t]
  __hip_bfloat16* uW1t = (__hip_bfloat16*)w; w += (size_t)L_SZ * (HD_SZ / 2) * 2;
  __hip_bfloat16* actb = (__hip_bfloat16*)w; w += (size_t)B_SZ * H_SZ * A_SZ * 2;
  float* z_cur = (float*)w;                  w += (size_t)B_SZ * L_SZ * 4;
  __hip_bfloat16* znb = (__hip_bfloat16*)w;  w += (size_t)B_SZ * L_SZ * 2;
  float* zu = (float*)w;                     w += (size_t)B_SZ * L_SZ * 4;
  float* tws = (float*)w;                    w += (size_t)B_SZ * HD_SZ * 4;
  __hip_bfloat16* hb = (__hip_bfloat16*)w;   w += (size_t)B_SZ * HD_SZ * 2;
  float* sig_acc = (float*)w;                w += (size_t)B_SZ * H_SZ * 4;
  float* bias3c = (float*)w;                 w += (size_t)HD_SZ * 4;
  float* zbias = (float*)w;                  w += (size_t)L_SZ * 4;

  float* trajOut = (float*)d_out;
  float* sigsOut = (float*)d_out + (size_t)B_SZ * H_SZ * L_SZ;

  dim3 tb(32, 8);
  transpose_cvt<<<dim3(HD_SZ / 32, (L_SZ + A_SZ) / 32), tb, 0, stream>>>(W1, W1t, L_SZ + A_SZ, HD_SZ);
  transpose_cvt<<<dim3(HD_SZ / 32, HD_SZ / 32), tb, 0, stream>>>(W2, W2t, HD_SZ, HD_SZ);
  transpose_cvt<<<dim3(L_SZ / 32, HD_SZ / 32), tb, 0, stream>>>(W3, W3c, HD_SZ, L_SZ);
  transpose_cvt<<<dim3((HD_SZ / 2) / 32, L_SZ / 32), tb, 0, stream>>>(uW1, uW1t, L_SZ, HD_SZ / 2);
  w34_kernel<<<dim3(HD_SZ / 16, L_SZ / 16), 256, 0, stream>>>(W3, uW1, W3c);
  bias3_kernel<<<2, 256, 0, stream>>>(b3, uW1, bias3c);

  cvt_bf16_kernel<<<(B_SZ * H_SZ * A_SZ / 4 + 255) / 256, 256, 0, stream>>>(
      actions, actb, B_SZ * H_SZ * A_SZ / 4);
  init_z_kernel<<<(B_SZ * L_SZ / 4 + 255) / 256, 256, 0, stream>>>(
      z0, z_cur, znb, B_SZ * L_SZ / 4);
  zero_kernel<<<(B_SZ * H_SZ + L_SZ + 255) / 256, 256, 0, stream>>>(
      sig_acc, B_SZ * H_SZ + L_SZ);  // sig_acc and (adjacent-ish) nothing else
  zero_kernel<<<(L_SZ + 255) / 256, 256, 0, stream>>>(zbias, L_SZ);

  const int KSPLIT_NONE = 1 << 30;

  // zu_0 = z0 @ uW1  (bias = 0)
  gemm_kernel<64, 128, 0><<<dim3(B_SZ / 64, L_SZ / 128), 256, 0, stream>>>(
      znb, L_SZ, nullptr, 0, KSPLIT_NONE, uW1t, zbias,
      L_SZ, L_SZ, zu, nullptr, nullptr, nullptr, nullptr, 0,
      nullptr, nullptr, nullptr, nullptr);

  for (int t = 0; t < H_SZ; ++t) {
    // GEMM1: [znb | actions_t] @ W1 + b1 -> tws
    gemm_kernel<64, 128, 0><<<dim3(B_SZ / 64, HD_SZ / 128), 256, 0, stream>>>(
        znb, L_SZ, actb + (size_t)t * A_SZ, H_SZ * A_SZ, L_SZ, W1t, b1,
        HD_SZ, L_SZ + A_SZ, tws, nullptr, nullptr, nullptr, nullptr, 0,
        nullptr, nullptr, nullptr, nullptr);
    ln_gelu_kernel<<<B_SZ, 256, 0, stream>>>(tws, g1, be1, hb);
    // GEMM2: h1 @ W2 + b2 -> tws
    gemm_kernel<64, 128, 0><<<dim3(B_SZ / 64, HD_SZ / 128), 256, 0, stream>>>(
        hb, HD_SZ, nullptr, 0, KSPLIT_NONE, W2t, b2,
        HD_SZ, HD_SZ, tws, nullptr, nullptr, nullptr, nullptr, 0,
        nullptr, nullptr, nullptr, nullptr);
    ln_gelu_kernel<<<B_SZ, 256, 0, stream>>>(tws, g2, be2, hb);
    // GEMM3': h2 @ [W3 | W34] -> z/traj update (cols<512) + zu/sig (cols>=512)
    gemm_kernel<64, 128, 4><<<dim3(B_SZ / 64, HD_SZ / 128), 256, 0, stream>>>(
        hb, HD_SZ, nullptr, 0, KSPLIT_NONE, W3c, bias3c,
        HD_SZ, HD_SZ, nullptr, z_cur, znb, trajOut, gate, t,
        zu, ub1, uW2, sig_acc);
  }
  softplus_kernel<<<(B_SZ * H_SZ + 255) / 256, 256, 0, stream>>>(
      sig_acc, ub2, sigsOut, B_SZ * H_SZ);
}

// Round 5
// 2253.207 us; speedup vs baseline: 1.1725x; 1.0583x over previous
//
#include <hip/hip_runtime.h>
#include <hip/hip_bf16.h>
#include <math.h>

#define B_SZ 4096
#define L_SZ 512
#define A_SZ 64
#define HD_SZ 1024
#define H_SZ 32

typedef __attribute__((ext_vector_type(8))) short bf16x8;
typedef __attribute__((ext_vector_type(4))) short s16x4;
typedef __attribute__((ext_vector_type(4))) float f32x4;

#define GLDS16(gsrc, ldst) __builtin_amdgcn_global_load_lds(              \
    (const __attribute__((address_space(1))) void*)(gsrc),                \
    (__attribute__((address_space(3))) void*)(ldst), 16, 0, 0)

template <int N> __device__ __forceinline__ void vmwait() {
  asm volatile("s_waitcnt vmcnt(%0)" :: "n"(N) : "memory");
}

__device__ __forceinline__ float gelu_exact(float x) {
  return 0.5f * x * (1.0f + erff(x * 0.70710678118654752f));
}

// ---------------------------------------------------------------------------
// 3-stage counted-vmcnt BK=64 GEMM: C[M,N] = A[M,K](bf16) x Wt[N,K](bf16)
// 4 waves (2 wm x 2 wn), wave-tile 32x64, 16x16x32 MFMA, b128 frag reads,
// XOR-swizzled LDS (byte col ^ ((row&7)<<4)), 64x128 block tile.
// Pipeline: 3 LDS slots, loads for kt+1,kt+2 stay in flight across barriers
// (vmcnt(12) steady-state, never 0 until the tail).
// MODE 0: outb = bf16(acc + bias[n])
// MODE 5: outf = acc + bias[n]                                  (f32)
// MODE 4: n0<512:  dz path: zn = z_cur + gs*(acc+bias); write z_cur, znb, traj
//         n0>=512: du path: zu += gs*(acc+bias); g=gelu(zu+ub1); atomic sig
// ---------------------------------------------------------------------------
template <int BM, int BN, int MODE>
__global__ __launch_bounds__(256, 2) void gemm_kernel(
    const __hip_bfloat16* __restrict__ A0, int a0s,
    const __hip_bfloat16* __restrict__ A1, int a1s, int ksplit,
    const __hip_bfloat16* __restrict__ Bt,
    const float* __restrict__ bias,
    int N, int K,
    float* __restrict__ outf,
    float* __restrict__ z_cur,
    __hip_bfloat16* __restrict__ znb,
    float* __restrict__ traj,
    const float* __restrict__ gate,
    int t,
    float* __restrict__ zu,
    const float* __restrict__ ub1v,
    const float* __restrict__ uW2,
    float* __restrict__ sig_acc,
    __hip_bfloat16* __restrict__ outb) {
  constexpr int BK = 64;
  constexpr int ROWB = BK * 2;            // 128 bytes per row
  constexpr int FM = BM / 32, FN = BN / 32;
  constexpr int ABYTES = BM * ROWB;
  constexpr int BUFB = (BM + BN) * ROWB;  // bytes per pipeline slot
  constexpr int LOADS = (BM + BN) / 32;   // GLDS16 per thread per k-tile
  __shared__ __align__(16) char lds[3 * BUFB];

  const int tid = threadIdx.x;
  const int m0 = blockIdx.x * BM, n0 = blockIdx.y * BN;
  const int wave = tid >> 6, lane = tid & 63;
  const int l15 = lane & 15, lg = lane >> 4;
  const int wm = wave >> 1, wn = wave & 1;
  const int NK = K / BK;

  f32x4 acc[FM][FN];
#pragma unroll
  for (int mi = 0; mi < FM; ++mi)
#pragma unroll
    for (int ni = 0; ni < FN; ++ni) acc[mi][ni] = (f32x4){0.f, 0.f, 0.f, 0.f};

  auto stage = [&](int slot, int kt) {
    char* dst = lds + slot * BUFB;
    const int k0 = kt * BK;
    const __hip_bfloat16* Aptr;
    int As, kloc;
    if (k0 < ksplit) { Aptr = A0; As = a0s; kloc = k0; }
    else             { Aptr = A1; As = a1s; kloc = k0 - ksplit; }
#pragma unroll
    for (int i = 0; i < BM / 32; ++i) {
      int off = tid * 16 + i * 4096;
      int r = off >> 7;
      int csw = (off & 127) ^ ((r & 7) << 4);
      GLDS16(Aptr + (size_t)(m0 + r) * As + kloc + (csw >> 1), dst + off);
    }
#pragma unroll
    for (int i = 0; i < BN / 32; ++i) {
      int off = tid * 16 + i * 4096;
      int r = off >> 7;
      int csw = (off & 127) ^ ((r & 7) << 4);
      GLDS16(Bt + (size_t)(n0 + r) * K + k0 + (csw >> 1), dst + ABYTES + off);
    }
  };

  // per-lane fragment byte offsets (row&7 == l15&7 for all frags)
  const int xrow = (l15 & 7) << 4;
  const int offs0 = (lg * 16) ^ xrow;      // k-substep 0
  const int aoff = (wm * (FM * 16) + l15) * ROWB;
  const int boff = ABYTES + (wn * (FN * 16) + l15) * ROWB;

  // prologue: 2 tiles in flight
  stage(0, 0);
  stage(1, 1);

  int buf = 0;
  for (int kt = 0; kt < NK; ++kt) {
    if (kt + 2 < NK) {
      int s2 = buf + 2; if (s2 >= 3) s2 -= 3;
      stage(s2, kt + 2);
      vmwait<2 * LOADS>();
    } else if (kt + 1 < NK) {
      vmwait<LOADS>();
    } else {
      vmwait<0>();
    }
    __builtin_amdgcn_s_barrier();
    asm volatile("" ::: "memory");

    const char* lb = lds + buf * BUFB;
    bf16x8 a_[FM][2], b_[FN][2];
#pragma unroll
    for (int mi = 0; mi < FM; ++mi) {
      a_[mi][0] = *(const bf16x8*)(lb + aoff + mi * (16 * ROWB) + offs0);
      a_[mi][1] = *(const bf16x8*)(lb + aoff + mi * (16 * ROWB) + (offs0 ^ 64));
    }
#pragma unroll
    for (int ni = 0; ni < FN; ++ni) {
      b_[ni][0] = *(const bf16x8*)(lb + boff + ni * (16 * ROWB) + offs0);
      b_[ni][1] = *(const bf16x8*)(lb + boff + ni * (16 * ROWB) + (offs0 ^ 64));
    }
#pragma unroll
    for (int s = 0; s < 2; ++s)
#pragma unroll
      for (int mi = 0; mi < FM; ++mi)
#pragma unroll
        for (int ni = 0; ni < FN; ++ni)
          acc[mi][ni] = __builtin_amdgcn_mfma_f32_16x16x32_bf16(
              a_[mi][s], b_[ni][s], acc[mi][ni], 0, 0, 0);

    asm volatile("" ::: "memory");
    __builtin_amdgcn_s_barrier();
    buf = (buf + 1 == 3) ? 0 : buf + 1;
  }

  // ---- epilogue -----------------------------------------------------------
  if constexpr (MODE == 0 || MODE == 5) {
#pragma unroll
    for (int mi = 0; mi < FM; ++mi) {
#pragma unroll
      for (int ni = 0; ni < FN; ++ni) {
        int gcol = n0 + wn * (FN * 16) + ni * 16 + l15;
        float bv = bias[gcol];
#pragma unroll
        for (int r = 0; r < 4; ++r) {
          int grow = m0 + wm * (FM * 16) + mi * 16 + lg * 4 + r;
          float v = acc[mi][ni][r] + bv;
          if constexpr (MODE == 0)
            outb[(size_t)grow * N + gcol] = __float2bfloat16(v);
          else
            outf[(size_t)grow * N + gcol] = v;
        }
      }
    }
  } else {
    const float gs = 1.f / (1.f + expf(-gate[0]));
    if (n0 < L_SZ) {
      // dz path: z update + traj + znb
#pragma unroll
      for (int mi = 0; mi < FM; ++mi) {
#pragma unroll
        for (int ni = 0; ni < FN; ++ni) {
          int gcol = n0 + wn * (FN * 16) + ni * 16 + l15;
          float bv = bias[gcol];
#pragma unroll
          for (int r = 0; r < 4; ++r) {
            int grow = m0 + wm * (FM * 16) + mi * 16 + lg * 4 + r;
            size_t zi = (size_t)grow * L_SZ + gcol;
            float zn = z_cur[zi] + gs * (acc[mi][ni][r] + bv);
            z_cur[zi] = zn;
            znb[zi] = __float2bfloat16(zn);
            traj[(size_t)grow * (H_SZ * L_SZ) + (size_t)t * L_SZ + gcol] = zn;
          }
        }
      }
    } else {
      // du path: zu update + gelu + uW2 dot -> sig_acc
#pragma unroll
      for (int mi = 0; mi < FM; ++mi) {
        float p[4] = {0.f, 0.f, 0.f, 0.f};
#pragma unroll
        for (int ni = 0; ni < FN; ++ni) {
          int gcol = n0 + wn * (FN * 16) + ni * 16 + l15;
          int j = gcol - L_SZ;
          float bv = bias[gcol];
          float ub = ub1v[j];
          float w2 = uW2[j];
#pragma unroll
          for (int r = 0; r < 4; ++r) {
            int grow = m0 + wm * (FM * 16) + mi * 16 + lg * 4 + r;
            size_t ui = (size_t)grow * L_SZ + j;
            float zun = zu[ui] + gs * (acc[mi][ni][r] + bv);
            zu[ui] = zun;
            p[r] += gelu_exact(zun + ub) * w2;
          }
        }
#pragma unroll
        for (int o = 1; o < 16; o <<= 1) {
#pragma unroll
          for (int r = 0; r < 4; ++r) p[r] += __shfl_xor(p[r], o);
        }
        if (l15 == 0) {
          int rowb = m0 + wm * (FM * 16) + mi * 16 + lg * 4;
#pragma unroll
          for (int r = 0; r < 4; ++r)
            atomicAdd(&sig_acc[(size_t)(rowb + r) * H_SZ + t], p[r]);
        }
      }
    }
  }
}

// ---------------------------------------------------------------------------
// Row LayerNorm (N=1024) + GELU, bf16 in -> bf16 out. One block per row.
// ---------------------------------------------------------------------------
__global__ __launch_bounds__(256) void ln_gelu_kernel(
    const __hip_bfloat16* __restrict__ x, const float* __restrict__ gam,
    const float* __restrict__ bet, __hip_bfloat16* __restrict__ out) {
  constexpr int N = HD_SZ;
  const int row = blockIdx.x;
  const int tid = threadIdx.x, lane = tid & 63, wave = tid >> 6;
  union { s16x4 sv; __hip_bfloat16 h[4]; } in;
  in.sv = *(const s16x4*)(x + (size_t)row * N + tid * 4);
  float v[4];
#pragma unroll
  for (int j = 0; j < 4; ++j) v[j] = __bfloat162float(in.h[j]);
  float s = v[0] + v[1] + v[2] + v[3];
  float s2 = v[0] * v[0] + v[1] * v[1] + v[2] * v[2] + v[3] * v[3];
#pragma unroll
  for (int o = 32; o; o >>= 1) {
    s += __shfl_xor(s, o);
    s2 += __shfl_xor(s2, o);
  }
  __shared__ float as_[4], as2_[4];
  if (lane == 0) { as_[wave] = s; as2_[wave] = s2; }
  __syncthreads();
  s = as_[0] + as_[1] + as_[2] + as_[3];
  s2 = as2_[0] + as2_[1] + as2_[2] + as2_[3];
  float mean = s * (1.f / N);
  float var = s2 * (1.f / N) - mean * mean;
  float rstd = rsqrtf(var + 1e-5f);
  f32x4 g = *(const f32x4*)(gam + tid * 4);
  f32x4 b = *(const f32x4*)(bet + tid * 4);
  union { __hip_bfloat16 h[4]; s16x4 sv; } o;
#pragma unroll
  for (int j = 0; j < 4; ++j) {
    float y = (v[j] - mean) * rstd * g[j] + b[j];
    o.h[j] = __float2bfloat16(gelu_exact(y));
  }
  *(s16x4*)(out + (size_t)row * N + tid * 4) = o.sv;
}

// ---------------------------------------------------------------------------
// prep / misc kernels
// ---------------------------------------------------------------------------
__global__ void transpose_cvt(const float* __restrict__ in,
                              __hip_bfloat16* __restrict__ out, int K, int N) {
  __shared__ float tile[32][33];
  const int n0 = blockIdx.x * 32, k0 = blockIdx.y * 32;
  const int tx = threadIdx.x, ty = threadIdx.y;  // (32, 8)
#pragma unroll
  for (int i = 0; i < 32; i += 8)
    tile[ty + i][tx] = in[(size_t)(k0 + ty + i) * N + (n0 + tx)];
  __syncthreads();
#pragma unroll
  for (int i = 0; i < 32; i += 8)
    out[(size_t)(n0 + ty + i) * K + (k0 + tx)] = __float2bfloat16(tile[tx][ty + i]);
}

// W34t[j][k] = sum_i W3[k][i]*uW1[i][j]  -> bf16 into W3c rows [512, 1024)
__global__ __launch_bounds__(256) void w34_kernel(
    const float* __restrict__ W3, const float* __restrict__ uW1,
    __hip_bfloat16* __restrict__ W3c) {
  __shared__ float tA[16][17];  // [k-local][i-local]
  __shared__ float tB[16][17];  // [i-local][j-local]
  const int k0 = blockIdx.x * 16, j0 = blockIdx.y * 16;
  const int tx = threadIdx.x & 15, ty = threadIdx.x >> 4;
  float acc = 0.f;
  for (int i0 = 0; i0 < L_SZ; i0 += 16) {
    tA[ty][tx] = W3[(size_t)(k0 + ty) * L_SZ + i0 + tx];
    tB[ty][tx] = uW1[(size_t)(i0 + ty) * (HD_SZ / 2) + j0 + tx];
    __syncthreads();
#pragma unroll
    for (int i = 0; i < 16; ++i) acc += tA[ty][i] * tB[i][tx];
    __syncthreads();
  }
  W3c[(size_t)(L_SZ + j0 + tx) * HD_SZ + k0 + ty] = __float2bfloat16(acc);
}

// bias3c[0:512) = b3 ; bias3c[512+j] = sum_i b3[i]*uW1[i][j]
__global__ void bias3_kernel(const float* __restrict__ b3,
                             const float* __restrict__ uW1,
                             float* __restrict__ bias3c) {
  int j = blockIdx.x * 256 + threadIdx.x;
  if (j >= L_SZ) return;
  bias3c[j] = b3[j];
  float s = 0.f;
  for (int i = 0; i < L_SZ; ++i) s += b3[i] * uW1[(size_t)i * (HD_SZ / 2) + j];
  bias3c[L_SZ + j] = s;
}

__global__ void cvt_bf16_kernel(const float* __restrict__ in,
                                __hip_bfloat16* __restrict__ out, int n4) {
  int i = blockIdx.x * 256 + threadIdx.x;
  if (i >= n4) return;
  f32x4 v = ((const f32x4*)in)[i];
  union { __hip_bfloat16 h[4]; s16x4 sv; } o;
#pragma unroll
  for (int j = 0; j < 4; ++j) o.h[j] = __float2bfloat16(v[j]);
  ((s16x4*)out)[i] = o.sv;
}

__global__ void init_z_kernel(const float* __restrict__ z0,
                              float* __restrict__ z_cur,
                              __hip_bfloat16* __restrict__ znb, int n4) {
  int i = blockIdx.x * 256 + threadIdx.x;
  if (i >= n4) return;
  f32x4 v = ((const f32x4*)z0)[i];
  ((f32x4*)z_cur)[i] = v;
  union { __hip_bfloat16 h[4]; s16x4 sv; } o;
#pragma unroll
  for (int j = 0; j < 4; ++j) o.h[j] = __float2bfloat16(v[j]);
  ((s16x4*)znb)[i] = o.sv;
}

__global__ void zero_kernel(float* __restrict__ p, int n) {
  int i = blockIdx.x * 256 + threadIdx.x;
  if (i < n) p[i] = 0.f;
}

__global__ void softplus_kernel(const float* __restrict__ acc,
                                const float* __restrict__ ub2,
                                float* __restrict__ out, int n) {
  int i = blockIdx.x * 256 + threadIdx.x;
  if (i >= n) return;
  float v = acc[i] + ub2[0];
  out[i] = v > 20.f ? v : log1pf(expf(v));
}

// ---------------------------------------------------------------------------
extern "C" void kernel_launch(void* const* d_in, const int* in_sizes, int n_in,
                              void* d_out, int out_size, void* d_ws,
                              size_t ws_size, hipStream_t stream) {
  const float* z0      = (const float*)d_in[0];
  const float* actions = (const float*)d_in[1];
  const float* W1  = (const float*)d_in[2];
  const float* b1  = (const float*)d_in[3];
  const float* g1  = (const float*)d_in[4];
  const float* be1 = (const float*)d_in[5];
  const float* W2  = (const float*)d_in[6];
  const float* b2  = (const float*)d_in[7];
  const float* g2  = (const float*)d_in[8];
  const float* be2 = (const float*)d_in[9];
  const float* W3  = (const float*)d_in[10];
  const float* b3  = (const float*)d_in[11];
  const float* uW1 = (const float*)d_in[12];
  const float* ub1 = (const float*)d_in[13];
  const float* uW2 = (const float*)d_in[14];
  const float* ub2 = (const float*)d_in[15];
  const float* gate = (const float*)d_in[16];

  char* w = (char*)d_ws;
  __hip_bfloat16* W1t = (__hip_bfloat16*)w;  w += (size_t)(L_SZ + A_SZ) * HD_SZ * 2;
  __hip_bfloat16* W2t = (__hip_bfloat16*)w;  w += (size_t)HD_SZ * HD_SZ * 2;
  __hip_bfloat16* W3c = (__hip_bfloat16*)w;  w += (size_t)HD_SZ * HD_SZ * 2;  // [W3t | W34t]
  __hip_bfloat16* uW1t = (__hip_bfloat16*)w; w += (size_t)L_SZ * (HD_SZ / 2) * 2;
  __hip_bfloat16* actb = (__hip_bfloat16*)w; w += (size_t)B_SZ * H_SZ * A_SZ * 2;
  float* z_cur = (float*)w;                  w += (size_t)B_SZ * L_SZ * 4;
  __hip_bfloat16* znb = (__hip_bfloat16*)w;  w += (size_t)B_SZ * L_SZ * 2;
  float* zu = (float*)w;                     w += (size_t)B_SZ * L_SZ * 4;
  __hip_bfloat16* tws = (__hip_bfloat16*)w;  w += (size_t)B_SZ * HD_SZ * 2;
  __hip_bfloat16* hb = (__hip_bfloat16*)w;   w += (size_t)B_SZ * HD_SZ * 2;
  float* sig_acc = (float*)w;                w += (size_t)B_SZ * H_SZ * 4;
  float* bias3c = (float*)w;                 w += (size_t)HD_SZ * 4;
  float* zbias = (float*)w;                  w += (size_t)L_SZ * 4;

  float* trajOut = (float*)d_out;
  float* sigsOut = (float*)d_out + (size_t)B_SZ * H_SZ * L_SZ;

  dim3 tb(32, 8);
  transpose_cvt<<<dim3(HD_SZ / 32, (L_SZ + A_SZ) / 32), tb, 0, stream>>>(W1, W1t, L_SZ + A_SZ, HD_SZ);
  transpose_cvt<<<dim3(HD_SZ / 32, HD_SZ / 32), tb, 0, stream>>>(W2, W2t, HD_SZ, HD_SZ);
  transpose_cvt<<<dim3(L_SZ / 32, HD_SZ / 32), tb, 0, stream>>>(W3, W3c, HD_SZ, L_SZ);
  transpose_cvt<<<dim3((HD_SZ / 2) / 32, L_SZ / 32), tb, 0, stream>>>(uW1, uW1t, L_SZ, HD_SZ / 2);
  w34_kernel<<<dim3(HD_SZ / 16, L_SZ / 16), 256, 0, stream>>>(W3, uW1, W3c);
  bias3_kernel<<<2, 256, 0, stream>>>(b3, uW1, bias3c);

  cvt_bf16_kernel<<<(B_SZ * H_SZ * A_SZ / 4 + 255) / 256, 256, 0, stream>>>(
      actions, actb, B_SZ * H_SZ * A_SZ / 4);
  init_z_kernel<<<(B_SZ * L_SZ / 4 + 255) / 256, 256, 0, stream>>>(
      z0, z_cur, znb, B_SZ * L_SZ / 4);
  zero_kernel<<<(B_SZ * H_SZ + 255) / 256, 256, 0, stream>>>(sig_acc, B_SZ * H_SZ);
  zero_kernel<<<(L_SZ + 255) / 256, 256, 0, stream>>>(zbias, L_SZ);

  const int KSPLIT_NONE = 1 << 30;

  // zu_0 = z0 @ uW1  (bias = 0), f32 out
  gemm_kernel<64, 128, 5><<<dim3(B_SZ / 64, L_SZ / 128), 256, 0, stream>>>(
      znb, L_SZ, nullptr, 0, KSPLIT_NONE, uW1t, zbias,
      L_SZ, L_SZ, zu, nullptr, nullptr, nullptr, nullptr, 0,
      nullptr, nullptr, nullptr, nullptr, nullptr);

  for (int t = 0; t < H_SZ; ++t) {
    // GEMM1: [znb | actions_t] @ W1 + b1 -> tws (bf16)
    gemm_kernel<64, 128, 0><<<dim3(B_SZ / 64, HD_SZ / 128), 256, 0, stream>>>(
        znb, L_SZ, actb + (size_t)t * A_SZ, H_SZ * A_SZ, L_SZ, W1t, b1,
        HD_SZ, L_SZ + A_SZ, nullptr, nullptr, nullptr, nullptr, nullptr, 0,
        nullptr, nullptr, nullptr, nullptr, tws);
    ln_gelu_kernel<<<B_SZ, 256, 0, stream>>>(tws, g1, be1, hb);
    // GEMM2: h1 @ W2 + b2 -> tws (bf16)
    gemm_kernel<64, 128, 0><<<dim3(B_SZ / 64, HD_SZ / 128), 256, 0, stream>>>(
        hb, HD_SZ, nullptr, 0, KSPLIT_NONE, W2t, b2,
        HD_SZ, HD_SZ, nullptr, nullptr, nullptr, nullptr, nullptr, 0,
        nullptr, nullptr, nullptr, nullptr, tws);
    ln_gelu_kernel<<<B_SZ, 256, 0, stream>>>(tws, g2, be2, hb);
    // GEMM3': h2 @ [W3 | W34] -> z/traj update (cols<512) + zu/sig (cols>=512)
    gemm_kernel<64, 128, 4><<<dim3(B_SZ / 64, HD_SZ / 128), 256, 0, stream>>>(
        hb, HD_SZ, nullptr, 0, KSPLIT_NONE, W3c, bias3c,
        HD_SZ, HD_SZ, nullptr, z_cur, znb, trajOut, gate, t,
        zu, ub1, uW2, sig_acc, nullptr);
  }
  softplus_kernel<<<(B_SZ * H_SZ + 255) / 256, 256, 0, stream>>>(
      sig_acc, ub2, sigsOut, B_SZ * H_SZ);
}